// Round 4
// baseline (4197.284 us; speedup 1.0000x reference)
//
#include <hip/hip_runtime.h>
#include <hip/hip_bf16.h>

// SRN: h_{t+1} = tanh(xW[:,t,:] + h_t @ U),  xW = X@W + b
// B=128, S=2048, D=H=256.
// k_xw : parallel GEMM X@W+b -> xw (f32). bf16 hi/lo 3-term split MFMA (~f32 accuracy).
//        512 blocks x 8 tiles of 64 rows, W converted once/block, double-buffered LDS,
//        non-draining barriers (lgkmcnt only).
// k_rec: sequential scan, 16 WGs x 8 chains, U^T persistent in registers (hi/lo),
//        h double-buffered in swizzled LDS. This round: prefetch issued at TOP of step,
//        raw s_barrier (no vmcnt drain), 3 independent MFMA accumulator chains.

#define BB 128
#define SS 2048
#define DD 256
#define HH 256

typedef __attribute__((ext_vector_type(8))) short bf16x8;
typedef __attribute__((ext_vector_type(4))) float f32x4;
typedef __attribute__((ext_vector_type(2))) unsigned int u32x2;
typedef __attribute__((ext_vector_type(4))) unsigned int u32x4;

__device__ __forceinline__ unsigned int bf16rne(float x) {
    unsigned int u = __float_as_uint(x);
    return (u + 0x7fffu + ((u >> 16) & 1u)) >> 16;
}
__device__ __forceinline__ float bf16f(unsigned int b) { return __uint_as_float(b << 16); }

__device__ __forceinline__ float fast_tanh(float z) {
    float e = __builtin_amdgcn_exp2f(z * 2.8853900817779268f);
    return 1.0f - 2.0f * __builtin_amdgcn_rcpf(e + 1.0f);
}

// barrier that does NOT drain vmcnt: LDS ordering only.
__device__ __forceinline__ void lds_barrier() {
    asm volatile("s_waitcnt lgkmcnt(0)" ::: "memory");
    __builtin_amdgcn_s_barrier();
    asm volatile("" ::: "memory");
}

// ---------------------------------------------------------------------------
// Kernel 1: xw[r][j] = sum_d X[r][d]*W[d][j] + bias[j]
// grid 512, block 512 (8 waves x 32-col slice). Each block: 8 tiles of 64 rows.
// ---------------------------------------------------------------------------
__launch_bounds__(512, 1)
__global__ void k_xw(const float* X, const float* __restrict__ W,
                     const float* __restrict__ bias, float* xw)
{
    __shared__ alignas(16) unsigned char lds[2][65536];  // per buf: hi[64][512B], lo at +32768

    const int tid  = threadIdx.x;
    const int lane = tid & 63;
    const int wv   = tid >> 6;
    const int lr   = lane & 15;
    const int lg   = lane >> 4;
    const int swz  = (lr & 7) << 4;
    const long rowB = (long)blockIdx.x * 512;

    // ---- W B-fragments (once per block): B[k][n], n = nb+nt*16+lr, k = ks*32+lg*8+e ----
    const int nb = wv * 32;
    bf16x8 WH[2][8], WL[2][8];
    #pragma unroll
    for (int nt = 0; nt < 2; ++nt) {
        int n = nb + nt * 16 + lr;
        #pragma unroll
        for (int ks = 0; ks < 8; ++ks) {
            int kbase = ks * 32 + lg * 8;
            bf16x8 wh, wl;
            #pragma unroll
            for (int e = 0; e < 8; ++e) {
                float w = W[(kbase + e) * 256 + n];
                unsigned int hb = bf16rne(w);
                wh[e] = (short)hb;
                wl[e] = (short)bf16rne(w - bf16f(hb));
            }
            WH[nt][ks] = wh; WL[nt][ks] = wl;
        }
    }
    float bz[2];
    bz[0] = bias[nb + lr];
    bz[1] = bias[nb + 16 + lr];

    // ---- staging helpers ----
    auto LOADT = [&](f32x4 (&rx)[8], int t) {
        long r0 = rowB + (long)t * 64;
        #pragma unroll
        for (int it = 0; it < 8; ++it) {
            int idx = tid + it * 512;
            rx[it] = *reinterpret_cast<const f32x4*>(X + (r0 + (idx >> 6)) * 256 + (idx & 63) * 4);
        }
    };
    auto CWRITE = [&](f32x4 (&rx)[8], int buf) {
        unsigned char* base = &lds[buf][0];
        #pragma unroll
        for (int it = 0; it < 8; ++it) {
            int idx = tid + it * 512;
            int r = idx >> 6, s = idx & 63;
            unsigned int hb[4], lb[4];
            #pragma unroll
            for (int e = 0; e < 4; ++e) {
                hb[e] = bf16rne(rx[it][e]);
                lb[e] = bf16rne(rx[it][e] - bf16f(hb[e]));
            }
            u32x2 hp, lp;
            hp[0] = hb[0] | (hb[1] << 16); hp[1] = hb[2] | (hb[3] << 16);
            lp[0] = lb[0] | (lb[1] << 16); lp[1] = lb[2] | (lb[3] << 16);
            int off = r * 512 + ((s * 8) ^ ((r & 7) << 4));
            *reinterpret_cast<u32x2*>(base + off)         = hp;
            *reinterpret_cast<u32x2*>(base + 32768 + off) = lp;
        }
    };
    auto TILE = [&](int t) {
        const unsigned char* base = &lds[t & 1][0];
        f32x4 acc[4][2];
        #pragma unroll
        for (int mt = 0; mt < 4; ++mt)
            #pragma unroll
            for (int nt = 0; nt < 2; ++nt)
                acc[mt][nt] = (f32x4){0.f, 0.f, 0.f, 0.f};
        #pragma unroll
        for (int ks = 0; ks < 8; ++ks) {
            #pragma unroll
            for (int mt = 0; mt < 4; ++mt) {
                int row = mt * 16 + lr;
                int kb  = (ks * 64 + lg * 16) ^ swz;
                bf16x8 ah = *reinterpret_cast<const bf16x8*>(base + row * 512 + kb);
                bf16x8 al = *reinterpret_cast<const bf16x8*>(base + 32768 + row * 512 + kb);
                #pragma unroll
                for (int nt = 0; nt < 2; ++nt) {
                    f32x4 c = acc[mt][nt];
                    c = __builtin_amdgcn_mfma_f32_16x16x32_bf16(ah, WH[nt][ks], c, 0, 0, 0);
                    c = __builtin_amdgcn_mfma_f32_16x16x32_bf16(al, WH[nt][ks], c, 0, 0, 0);
                    c = __builtin_amdgcn_mfma_f32_16x16x32_bf16(ah, WL[nt][ks], c, 0, 0, 0);
                    acc[mt][nt] = c;
                }
            }
        }
        long r0 = rowB + (long)t * 64;
        #pragma unroll
        for (int mt = 0; mt < 4; ++mt)
            #pragma unroll
            for (int nt = 0; nt < 2; ++nt)
                #pragma unroll
                for (int r = 0; r < 4; ++r) {
                    long orow = r0 + mt * 16 + lg * 4 + r;
                    int  ocol = nb + nt * 16 + lr;
                    xw[orow * 256 + ocol] = acc[mt][nt][r] + bz[nt];
                }
    };

    // ---- pipeline: stage(0); loop { load(t+1) | mfma(t) | cwrite(t+1) | barrier } ----
    {
        f32x4 rx[8];
        LOADT(rx, 0);
        CWRITE(rx, 0);
    }
    lds_barrier();
    for (int t = 0; t < 8; ++t) {
        f32x4 nx[8];
        if (t < 7) LOADT(nx, t + 1);
        __builtin_amdgcn_sched_barrier(0);   // keep next-tile loads issued first
        TILE(t);
        if (t < 7) CWRITE(nx, (t + 1) & 1);
        lds_barrier();
    }
}

// ---------------------------------------------------------------------------
// Kernel 2: sequential scan. grid 16 x block 256 (4 waves).
// z^T = U^T (regs) x h^T (LDS). C: col=lane&15=chain, row=(lane>>4)*4+reg = j.
// ---------------------------------------------------------------------------
__launch_bounds__(256, 1)
__global__ void k_rec(const float* __restrict__ xw, const float* __restrict__ U,
                      float* __restrict__ out)
{
    __shared__ alignas(16) unsigned char hlds[2 * 16384];

    const int tid  = threadIdx.x;
    const int lane = tid & 63;
    const int wv   = tid >> 6;          // j slice of 64
    const int lr   = lane & 15;
    const int lg   = lane >> 4;
    const int swz  = (lr & 7) << 4;
    const int jsl  = wv * 64;
    const bool act = (lr < 8);
    const int  m   = lr;
    const long cg  = (long)blockIdx.x * 8 + (m & 7);
    const float* xbase = xw + cg * (long)(SS * 256);

    // zero both LDS buffers (h0 = 0; pad chains stay 0)
    {
        u32x4 z4; z4[0] = 0; z4[1] = 0; z4[2] = 0; z4[3] = 0;
        #pragma unroll
        for (int i = 0; i < 8; ++i)
            *reinterpret_cast<u32x4*>(hlds + tid * 128 + i * 16) = z4;
    }

    // U^T A-fragments (persistent): A[row=j][k=i] = U[i][j]
    bf16x8 UHf[4][8], ULf[4][8];
    #pragma unroll
    for (int jt = 0; jt < 4; ++jt) {
        int j = jsl + jt * 16 + lr;
        #pragma unroll
        for (int ks = 0; ks < 8; ++ks) {
            int kbase = ks * 32 + lg * 8;
            bf16x8 uh, ul;
            #pragma unroll
            for (int e = 0; e < 8; ++e) {
                float u = U[(kbase + e) * 256 + j];
                unsigned int hb = bf16rne(u);
                uh[e] = (short)hb;
                ul[e] = (short)bf16rne(u - bf16f(hb));
            }
            UHf[jt][ks] = uh; ULf[jt][ks] = ul;
        }
    }
    __syncthreads();

    // xW prefetch registers, 2 steps deep
    f32x4 pxA[4], pxB[4];
    if (act) {
        #pragma unroll
        for (int jt = 0; jt < 4; ++jt) {
            pxA[jt] = *reinterpret_cast<const f32x4*>(xbase + 0 * 256 + jsl + jt * 16 + lg * 4);
            pxB[jt] = *reinterpret_cast<const f32x4*>(xbase + 1 * 256 + jsl + jt * 16 + lg * 4);
        }
    }

    auto STEP = [&](f32x4 (&pxu)[4], int t, int rb, int wb) {
        // 1. issue xW prefetch for t+2 FIRST — latency hides under this step's MFMA
        f32x4 nx[4];
        if (act) {
            int tn = t + 2; if (tn > SS - 1) tn = SS - 1;
            #pragma unroll
            for (int jt = 0; jt < 4; ++jt)
                nx[jt] = *reinterpret_cast<const f32x4*>(xbase + (long)tn * 256 + jsl + jt * 16 + lg * 4);
        }
        __builtin_amdgcn_sched_barrier(0);   // pin prefetch issue at top of step

        const unsigned char* rbuf = hlds + rb * 16384;
        unsigned char*       wbuf = hlds + wb * 16384;

        // 2. B-fragments of h from LDS
        bf16x8 hhf[8], hlf[8];
        #pragma unroll
        for (int ks = 0; ks < 8; ++ks) {
            int kb = (ks * 64 + lg * 16) ^ swz;
            hhf[ks] = *reinterpret_cast<const bf16x8*>(rbuf + lr * 512 + kb);
            hlf[ks] = *reinterpret_cast<const bf16x8*>(rbuf + 8192 + lr * 512 + kb);
        }

        // 3. MFMA: 3 independent accumulator chains per jt (12 chains x 8 deep)
        f32x4 aP[4], aQ[4], aR[4];
        #pragma unroll
        for (int jt = 0; jt < 4; ++jt) {
            aP[jt] = (f32x4){0.f, 0.f, 0.f, 0.f};
            aQ[jt] = (f32x4){0.f, 0.f, 0.f, 0.f};
            aR[jt] = (f32x4){0.f, 0.f, 0.f, 0.f};
        }
        #pragma unroll
        for (int ks = 0; ks < 8; ++ks) {
            #pragma unroll
            for (int jt = 0; jt < 4; ++jt) {
                aP[jt] = __builtin_amdgcn_mfma_f32_16x16x32_bf16(UHf[jt][ks], hhf[ks], aP[jt], 0, 0, 0);
                aQ[jt] = __builtin_amdgcn_mfma_f32_16x16x32_bf16(ULf[jt][ks], hhf[ks], aQ[jt], 0, 0, 0);
                aR[jt] = __builtin_amdgcn_mfma_f32_16x16x32_bf16(UHf[jt][ks], hlf[ks], aR[jt], 0, 0, 0);
            }
        }

        // 4. epilogue: z = sum + xW(t); h = tanh(z); write bf16 hi/lo to wbuf
        if (act) {
            #pragma unroll
            for (int jt = 0; jt < 4; ++jt) {
                unsigned int hbits[4], lbits[4];
                #pragma unroll
                for (int r = 0; r < 4; ++r) {
                    float z = ((aP[jt][r] + aQ[jt][r]) + aR[jt][r]) + pxu[jt][r];
                    float h = fast_tanh(z);
                    hbits[r] = bf16rne(h);
                    lbits[r] = bf16rne(h - bf16f(hbits[r]));
                }
                int j0 = jsl + jt * 16 + lg * 4;
                int kb = (j0 * 2) ^ (m << 4);
                u32x2 hp, lp;
                hp[0] = hbits[0] | (hbits[1] << 16); hp[1] = hbits[2] | (hbits[3] << 16);
                lp[0] = lbits[0] | (lbits[1] << 16); lp[1] = lbits[2] | (lbits[3] << 16);
                *reinterpret_cast<u32x2*>(wbuf + m * 512 + kb)        = hp;
                *reinterpret_cast<u32x2*>(wbuf + 8192 + m * 512 + kb) = lp;
            }
            // 5. commit prefetch (vmcnt wait lands here, covered by the step's compute)
            #pragma unroll
            for (int jt = 0; jt < 4; ++jt) pxu[jt] = nx[jt];
        }
        // 6. LDS-only barrier — vmcnt stays outstanding across steps
        lds_barrier();
    };

    for (int t = 0; t < SS; t += 2) {
        STEP(pxA, t,     0, 1);
        STEP(pxB, t + 1, 1, 0);
    }

    // final h from LDS buffer 0 (last write target): h = hi + lo
    if (act) {
        #pragma unroll
        for (int jt = 0; jt < 4; ++jt) {
            int j0 = jsl + jt * 16 + lg * 4;
            int kb = (j0 * 2) ^ (m << 4);
            u32x2 hp = *reinterpret_cast<const u32x2*>(hlds + m * 512 + kb);
            u32x2 lp = *reinterpret_cast<const u32x2*>(hlds + 8192 + m * 512 + kb);
            f32x4 o;
            o[0] = bf16f(hp[0] & 0xffffu) + bf16f(lp[0] & 0xffffu);
            o[1] = bf16f(hp[0] >> 16)     + bf16f(lp[0] >> 16);
            o[2] = bf16f(hp[1] & 0xffffu) + bf16f(lp[1] & 0xffffu);
            o[3] = bf16f(hp[1] >> 16)     + bf16f(lp[1] >> 16);
            *reinterpret_cast<f32x4*>(out + cg * 256 + jsl + jt * 16 + lg * 4) = o;
        }
    }
}

extern "C" void kernel_launch(void* const* d_in, const int* in_sizes, int n_in,
                              void* d_out, int out_size, void* d_ws, size_t ws_size,
                              hipStream_t stream)
{
    (void)in_sizes; (void)n_in; (void)out_size;
    const float* X    = (const float*)d_in[0];
    const float* W    = (const float*)d_in[1];
    const float* U    = (const float*)d_in[2];
    const float* bias = (const float*)d_in[3];
    float* out = (float*)d_out;

    const size_t need = (size_t)BB * SS * HH * sizeof(float);  // 256 MB
    float* xw = (ws_size >= need) ? (float*)d_ws : (float*)d_in[0];

    k_xw<<<dim3(512), dim3(512), 0, stream>>>(X, W, bias, xw);
    k_rec<<<dim3(16), dim3(256), 0, stream>>>(xw, U, out);
}

// Round 6
// 2802.668 us; speedup vs baseline: 1.4976x; 1.4976x over previous
//
#include <hip/hip_runtime.h>
#include <hip/hip_bf16.h>

// SRN: h_{t+1} = tanh(xW[:,t,:] + h_t @ U),  xW = X@W + b.  B=128,S=2048,D=H=256.
// k_xw : parallel GEMM X@W+b -> xw (f32), bf16 hi/lo 3-term split MFMA.
//        TR=1 writes xw transposed [t][b][j] (coalesced k_rec prefetch slabs).
// k_rec: sequential scan. 8 WGs x 16 chains, 512 thr (8 waves = 2/SIMD: fills the
//        matrix pipe — single wave issues 1 MFMA/16cyc, measured R2/R4).
//        Each wave owns 32 j (2 jt): U-frags 128 VGPR. Single chained accumulator
//        (R4's 3-acc cost +426 VALU cyc/step). h double-buffered in swizzled LDS;
//        lgkmcnt-only barrier; xW prefetch refilled in place, consumed 2 steps later.

#define BB 128
#define SS 2048
#define DD 256
#define HH 256

typedef __attribute__((ext_vector_type(8))) short bf16x8;
typedef __attribute__((ext_vector_type(4))) float f32x4;
typedef __attribute__((ext_vector_type(2))) unsigned int u32x2;
typedef __attribute__((ext_vector_type(4))) unsigned int u32x4;

__device__ __forceinline__ unsigned int bf16rne(float x) {
    unsigned int u = __float_as_uint(x);
    return (u + 0x7fffu + ((u >> 16) & 1u)) >> 16;
}
__device__ __forceinline__ float bf16f(unsigned int b) { return __uint_as_float(b << 16); }

__device__ __forceinline__ float fast_tanh(float z) {
    float e = __builtin_amdgcn_exp2f(z * 2.8853900817779268f);
    return 1.0f - 2.0f * __builtin_amdgcn_rcpf(e + 1.0f);
}

// barrier that does NOT drain vmcnt: LDS ordering only.
__device__ __forceinline__ void lds_barrier() {
    asm volatile("s_waitcnt lgkmcnt(0)" ::: "memory");
    __builtin_amdgcn_s_barrier();
    asm volatile("" ::: "memory");
}

// ---------------------------------------------------------------------------
// Kernel 1: xw = X@W + b. grid 512, block 512 (8 waves x 32-col slice),
// 8 tiles of 64 rows per block. TR: store [t][b][j] (t=r&2047, b=r>>11).
// ---------------------------------------------------------------------------
template<int TR>
__launch_bounds__(512, 1)
__global__ void k_xw(const float* X, const float* __restrict__ W,
                     const float* __restrict__ bias, float* xw)
{
    __shared__ alignas(16) unsigned char lds[2][65536];  // hi[64][512B], lo at +32768

    const int tid  = threadIdx.x;
    const int lane = tid & 63;
    const int wv   = tid >> 6;
    const int lr   = lane & 15;
    const int lg   = lane >> 4;
    const int swz  = (lr & 7) << 4;
    const long rowB = (long)blockIdx.x * 512;

    // W B-fragments once per block: B[k][n], n = nb+nt*16+lr, k = ks*32+lg*8+e
    const int nb = wv * 32;
    bf16x8 WH[2][8], WL[2][8];
    #pragma unroll
    for (int nt = 0; nt < 2; ++nt) {
        int n = nb + nt * 16 + lr;
        #pragma unroll
        for (int ks = 0; ks < 8; ++ks) {
            int kbase = ks * 32 + lg * 8;
            bf16x8 wh, wl;
            #pragma unroll
            for (int e = 0; e < 8; ++e) {
                float w = W[(kbase + e) * 256 + n];
                unsigned int hb = bf16rne(w);
                wh[e] = (short)hb;
                wl[e] = (short)bf16rne(w - bf16f(hb));
            }
            WH[nt][ks] = wh; WL[nt][ks] = wl;
        }
    }
    float bz[2];
    bz[0] = bias[nb + lr];
    bz[1] = bias[nb + 16 + lr];

    auto LOADT = [&](f32x4 (&rx)[8], int t) {
        long r0 = rowB + (long)t * 64;
        #pragma unroll
        for (int it = 0; it < 8; ++it) {
            int idx = tid + it * 512;
            rx[it] = *reinterpret_cast<const f32x4*>(X + (r0 + (idx >> 6)) * 256 + (idx & 63) * 4);
        }
    };
    auto CWRITE = [&](f32x4 (&rx)[8], int buf) {
        unsigned char* base = &lds[buf][0];
        #pragma unroll
        for (int it = 0; it < 8; ++it) {
            int idx = tid + it * 512;
            int r = idx >> 6, s = idx & 63;
            unsigned int hb[4], lb[4];
            #pragma unroll
            for (int e = 0; e < 4; ++e) {
                hb[e] = bf16rne(rx[it][e]);
                lb[e] = bf16rne(rx[it][e] - bf16f(hb[e]));
            }
            u32x2 hp, lp;
            hp[0] = hb[0] | (hb[1] << 16); hp[1] = hb[2] | (hb[3] << 16);
            lp[0] = lb[0] | (lb[1] << 16); lp[1] = lb[2] | (lb[3] << 16);
            int off = r * 512 + ((s * 8) ^ ((r & 7) << 4));
            *reinterpret_cast<u32x2*>(base + off)         = hp;
            *reinterpret_cast<u32x2*>(base + 32768 + off) = lp;
        }
    };
    auto TILE = [&](int t) {
        const unsigned char* base = &lds[t & 1][0];
        f32x4 acc[4][2];
        #pragma unroll
        for (int mt = 0; mt < 4; ++mt)
            #pragma unroll
            for (int nt = 0; nt < 2; ++nt)
                acc[mt][nt] = (f32x4){0.f, 0.f, 0.f, 0.f};
        #pragma unroll
        for (int ks = 0; ks < 8; ++ks) {
            #pragma unroll
            for (int mt = 0; mt < 4; ++mt) {
                int row = mt * 16 + lr;
                int kb  = (ks * 64 + lg * 16) ^ swz;
                bf16x8 ah = *reinterpret_cast<const bf16x8*>(base + row * 512 + kb);
                bf16x8 al = *reinterpret_cast<const bf16x8*>(base + 32768 + row * 512 + kb);
                #pragma unroll
                for (int nt = 0; nt < 2; ++nt) {
                    f32x4 c = acc[mt][nt];
                    c = __builtin_amdgcn_mfma_f32_16x16x32_bf16(ah, WH[nt][ks], c, 0, 0, 0);
                    c = __builtin_amdgcn_mfma_f32_16x16x32_bf16(al, WH[nt][ks], c, 0, 0, 0);
                    c = __builtin_amdgcn_mfma_f32_16x16x32_bf16(ah, WL[nt][ks], c, 0, 0, 0);
                    acc[mt][nt] = c;
                }
            }
        }
        long r0 = rowB + (long)t * 64;
        #pragma unroll
        for (int mt = 0; mt < 4; ++mt)
            #pragma unroll
            for (int nt = 0; nt < 2; ++nt)
                #pragma unroll
                for (int rr = 0; rr < 4; ++rr) {
                    long orow = r0 + mt * 16 + lg * 4 + rr;
                    int  ocol = nb + nt * 16 + lr;
                    long addr = TR ? (((orow & 2047) << 15) + ((orow >> 11) << 8) + ocol)
                                   : (orow * 256 + ocol);
                    xw[addr] = acc[mt][nt][rr] + bz[nt];
                }
    };

    {
        f32x4 rx[8];
        LOADT(rx, 0);
        CWRITE(rx, 0);
    }
    lds_barrier();
    for (int t = 0; t < 8; ++t) {
        f32x4 nx[8];
        if (t < 7) LOADT(nx, t + 1);
        __builtin_amdgcn_sched_barrier(0);
        TILE(t);
        if (t < 7) CWRITE(nx, (t + 1) & 1);
        lds_barrier();
    }
}

// ---------------------------------------------------------------------------
// Kernel 2: sequential scan. grid 8, block 512 (8 waves, 2/SIMD).
// z^T = U^T (regs) x h^T (LDS). C: col=lane&15=chain (16 real), row=lg*4+r=j.
// Wave wv owns j in [wv*32, wv*32+32) (2 jt). LDS: 2 x (hi[16][512] + lo[16][512]).
// ---------------------------------------------------------------------------
template<int TR>
__launch_bounds__(512, 2)
__global__ void k_rec(const float* __restrict__ xw, const float* __restrict__ U,
                      float* __restrict__ out)
{
    __shared__ alignas(16) unsigned char hlds[2 * 16384];

    const int tid  = threadIdx.x;
    const int lane = tid & 63;
    const int wv   = tid >> 6;          // 0..7 -> j slice of 32
    const int lr   = lane & 15;
    const int lg   = lane >> 4;
    const int swz  = (lr & 7) << 4;
    const int jsl  = wv * 32;
    const int m    = lr;                // chain in WG, 0..15 all real
    const long cgl = (long)blockIdx.x * 16 + m;

    // zero both LDS buffers (h0 = 0)
    {
        u32x4 z4; z4[0] = 0; z4[1] = 0; z4[2] = 0; z4[3] = 0;
        #pragma unroll
        for (int i = 0; i < 4; ++i)
            *reinterpret_cast<u32x4*>(hlds + tid * 64 + i * 16) = z4;
    }

    // U^T A-fragments (persistent, 128 VGPR): A[row=j][k=i] = U[i][j]
    bf16x8 UHf[2][8], ULf[2][8];
    #pragma unroll
    for (int jt = 0; jt < 2; ++jt) {
        int j = jsl + jt * 16 + lr;
        #pragma unroll
        for (int ks = 0; ks < 8; ++ks) {
            int kbase = ks * 32 + lg * 8;
            bf16x8 uh, ul;
            #pragma unroll
            for (int e = 0; e < 8; ++e) {
                float u = U[(kbase + e) * 256 + j];
                unsigned int hb = bf16rne(u);
                uh[e] = (short)hb;
                ul[e] = (short)bf16rne(u - bf16f(hb));
            }
            UHf[jt][ks] = uh; ULf[jt][ks] = ul;
        }
    }
    __syncthreads();

    auto XADDR = [&](int t, int jt) -> const f32x4* {
        long a = TR ? (((long)t << 15) + (cgl << 8) + (jsl + jt * 16 + lg * 4))
                    : (cgl * (long)(SS * 256) + (long)t * 256 + (jsl + jt * 16 + lg * 4));
        return reinterpret_cast<const f32x4*>(xw + a);
    };

    // xW prefetch registers, 2 steps deep (all lanes real)
    f32x4 pxA[2], pxB[2];
    #pragma unroll
    for (int jt = 0; jt < 2; ++jt) {
        pxA[jt] = *XADDR(0, jt);
        pxB[jt] = *XADDR(1, jt);
    }

    auto STEP = [&](f32x4 (&pxu)[2], int t, int rb, int wb) {
        const unsigned char* rbuf = hlds + rb * 16384;
        unsigned char*       wbuf = hlds + wb * 16384;

        // B-fragments of h from LDS: B[k][n=lr], k = ks*32 + lg*8 + e
        // MFMA: single chained accumulator per jt, 3 split terms (drop lo*lo).
        f32x4 acc[2];
        acc[0] = (f32x4){0.f, 0.f, 0.f, 0.f};
        acc[1] = (f32x4){0.f, 0.f, 0.f, 0.f};
        #pragma unroll
        for (int ks = 0; ks < 8; ++ks) {
            int kb = (ks * 64 + lg * 16) ^ swz;
            bf16x8 hh = *reinterpret_cast<const bf16x8*>(rbuf + lr * 512 + kb);
            bf16x8 hl = *reinterpret_cast<const bf16x8*>(rbuf + 8192 + lr * 512 + kb);
            #pragma unroll
            for (int jt = 0; jt < 2; ++jt) {
                f32x4 c = acc[jt];
                c = __builtin_amdgcn_mfma_f32_16x16x32_bf16(UHf[jt][ks], hh, c, 0, 0, 0);
                c = __builtin_amdgcn_mfma_f32_16x16x32_bf16(ULf[jt][ks], hh, c, 0, 0, 0);
                c = __builtin_amdgcn_mfma_f32_16x16x32_bf16(UHf[jt][ks], hl, c, 0, 0, 0);
                acc[jt] = c;
            }
        }

        // epilogue (all 64 lanes): z = acc + xW(t); h = tanh(z); bf16 hi/lo -> wbuf
        #pragma unroll
        for (int jt = 0; jt < 2; ++jt) {
            unsigned int hbits[4], lbits[4];
            #pragma unroll
            for (int r = 0; r < 4; ++r) {
                float z = acc[jt][r] + pxu[jt][r];
                float h = fast_tanh(z);
                hbits[r] = bf16rne(h);
                lbits[r] = bf16rne(h - bf16f(hbits[r]));
            }
            int j0 = jsl + jt * 16 + lg * 4;
            int kb = (j0 * 2) ^ ((m & 7) << 4);
            u32x2 hp, lp;
            hp[0] = hbits[0] | (hbits[1] << 16); hp[1] = hbits[2] | (hbits[3] << 16);
            lp[0] = lbits[0] | (lbits[1] << 16); lp[1] = lbits[2] | (lbits[3] << 16);
            *reinterpret_cast<u32x2*>(wbuf + m * 512 + kb)        = hp;
            *reinterpret_cast<u32x2*>(wbuf + 8192 + m * 512 + kb) = lp;
        }
        // refill in place: consumed 2 steps later; vmcnt never drains at barrier
        {
            int tn = t + 2; if (tn > SS - 1) tn = SS - 1;
            #pragma unroll
            for (int jt = 0; jt < 2; ++jt) pxu[jt] = *XADDR(tn, jt);
        }
        lds_barrier();
    };

    for (int t = 0; t < SS; t += 2) {
        STEP(pxA, t,     0, 1);
        STEP(pxB, t + 1, 1, 0);
    }

    // final h from LDS buffer 0: h = hi + lo
    #pragma unroll
    for (int jt = 0; jt < 2; ++jt) {
        int j0 = jsl + jt * 16 + lg * 4;
        int kb = (j0 * 2) ^ ((m & 7) << 4);
        u32x2 hp = *reinterpret_cast<const u32x2*>(hlds + m * 512 + kb);
        u32x2 lp = *reinterpret_cast<const u32x2*>(hlds + 8192 + m * 512 + kb);
        f32x4 o;
        o[0] = bf16f(hp[0] & 0xffffu) + bf16f(lp[0] & 0xffffu);
        o[1] = bf16f(hp[0] >> 16)     + bf16f(lp[0] >> 16);
        o[2] = bf16f(hp[1] & 0xffffu) + bf16f(lp[1] & 0xffffu);
        o[3] = bf16f(hp[1] >> 16)     + bf16f(lp[1] >> 16);
        *reinterpret_cast<f32x4*>(out + cgl * 256 + j0) = o;
    }
}

extern "C" void kernel_launch(void* const* d_in, const int* in_sizes, int n_in,
                              void* d_out, int out_size, void* d_ws, size_t ws_size,
                              hipStream_t stream)
{
    (void)in_sizes; (void)n_in; (void)out_size;
    const float* X    = (const float*)d_in[0];
    const float* W    = (const float*)d_in[1];
    const float* U    = (const float*)d_in[2];
    const float* bias = (const float*)d_in[3];
    float* out = (float*)d_out;

    const size_t need = (size_t)BB * SS * HH * sizeof(float);  // 256 MB
    if (ws_size >= need) {
        float* xw = (float*)d_ws;
        k_xw<1><<<dim3(512), dim3(512), 0, stream>>>(X, W, bias, xw);
        k_rec<1><<<dim3(8), dim3(512), 0, stream>>>(xw, U, out);
    } else {
        // in-place over X requires the untransposed layout (block-local overwrite)
        float* xw = (float*)d_in[0];
        k_xw<0><<<dim3(512), dim3(512), 0, stream>>>(X, W, bias, xw);
        k_rec<0><<<dim3(8), dim3(512), 0, stream>>>(xw, U, out);
    }
}